// Round 3
// baseline (336.490 us; speedup 1.0000x reference)
//
#include <hip/hip_runtime.h>
#include <math.h>

#define NN 10000
#define BB 4
#define EE 160000
#define CC 64
#define CE 16

// ---- workspace layout (bytes) ----
static constexpr size_t OFF_XPA    = 0;          // float[NN*BB*CC]
static constexpr size_t OFF_XPB    = 10240000;   // float[NN*BB*CC]
static constexpr size_t OFF_SA     = 20480000;   // float[NN*BB]
static constexpr size_t OFF_SB     = 20640000;   // float[NN*BB]
static constexpr size_t OFF_VECS   = 20800000;   // float[288]
static constexpr size_t OFF_COUNTS = 20801280;   // int[NN]
static constexpr size_t OFF_CURSOR = 20841280;   // int[NN]
static constexpr size_t OFF_OFFS   = 20881280;   // int[NN+1]
static constexpr size_t OFF_RECS   = 20921344;   // int2[EE]   (1.28 MB)
static constexpr size_t OFF_ATT    = 22201344;   // float4[EE] (2.56 MB)
static constexpr size_t OFF_SE12   = 24761344;   // float2[EE] (1.28 MB)
static constexpr size_t OFF_ORDER  = 26041344;   // int[NN]    -> total ~26.1 MB

__device__ __forceinline__ float sigmoidf_(float x) {
    // v_rcp_f32 (~1ulp) instead of IEEE divide; validated absmax-identical in r1/r2
    return __builtin_amdgcn_rcpf(1.0f + __expf(-x));
}

// histogram of dst + (block 0) fold q@aw_q, k@aw_k, w_e@aw_e for both layers
__global__ void hist_vecs_kernel(const int* __restrict__ ei, int* __restrict__ counts,
                                 const float* __restrict__ q1, const float* __restrict__ k1,
                                 const float* __restrict__ aw1, const float* __restrict__ we1,
                                 const float* __restrict__ q2, const float* __restrict__ k2,
                                 const float* __restrict__ aw2, const float* __restrict__ we2,
                                 float* __restrict__ vecs) {
    int e = blockIdx.x * blockDim.x + threadIdx.x;
    if (e < EE) atomicAdd(&counts[ei[EE + e]], 1);
    if (blockIdx.x == 0) {
        int t = threadIdx.x;
        if (t < 64) {
            float a = 0.f, b = 0.f, c = 0.f, d = 0.f;
            for (int j = 0; j < 64; ++j) {
                a = fmaf(q1[t * 64 + j], aw1[j], a);
                b = fmaf(k1[t * 64 + j], aw1[64 + j], b);
                c = fmaf(q2[t * 64 + j], aw2[j], c);
                d = fmaf(k2[t * 64 + j], aw2[64 + j], d);
            }
            vecs[t] = a; vecs[64 + t] = b; vecs[144 + t] = c; vecs[208 + t] = d;
        }
        if (t < 16) {
            float a = 0.f, b = 0.f;
            for (int j = 0; j < 64; ++j) {
                a = fmaf(we1[t * 64 + j], aw1[128 + j], a);
                b = fmaf(we2[t * 64 + j], aw2[128 + j], b);
            }
            vecs[128 + t] = a; vecs[272 + t] = b;
        }
    }
}

// single-block: exclusive scan of counts -> offs, THEN counting-sort nodes by
// degree descending -> order[] (LPT schedule for conv_out). One launch.
__global__ __launch_bounds__(1024) void scan_order_kernel(const int* __restrict__ counts,
                                                          int* __restrict__ offs,
                                                          int* __restrict__ order) {
    __shared__ int hist[1024];
    __shared__ int cur[1024];
    __shared__ int startb[1024];
    __shared__ int wsum[16];
    int t = threadIdx.x;
    hist[t] = 0; cur[t] = 0;
    int lane = t & 63, wid = t >> 6;
    // ---- phase 1: exclusive scan ----
    int v[10];
    int s = 0;
    #pragma unroll
    for (int j = 0; j < 10; ++j) {
        int i = t * 10 + j;
        v[j] = (i < NN) ? counts[i] : 0;
        s += v[j];
    }
    int ps = s;
    #pragma unroll
    for (int off = 1; off < 64; off <<= 1) {
        int u = __shfl_up(ps, off, 64);
        if (lane >= off) ps += u;
    }
    if (lane == 63) wsum[wid] = ps;
    __syncthreads();   // also covers hist/cur zero-init
    int wbase = 0;
    for (int w = 0; w < wid; ++w) wbase += wsum[w];
    int tb = wbase + ps - s;  // exclusive prefix
    #pragma unroll
    for (int j = 0; j < 10; ++j) {
        int i = t * 10 + j;
        if (i < NN) offs[i] = tb;
        tb += v[j];
    }
    if (t == 1023) offs[NN] = tb;
    // ---- phase 2: degree histogram ----
    #pragma unroll
    for (int j = 0; j < 10; ++j) {
        int i = t * 10 + j;
        if (i < NN) {
            int d = v[j] > 1023 ? 1023 : v[j];
            atomicAdd(&hist[d], 1);
        }
    }
    __syncthreads();
    // ---- phase 3: suffix sums (descending bins) ----
    int r = 1023 - t;
    int hv = hist[r];
    int ps2 = hv;
    #pragma unroll
    for (int off = 1; off < 64; off <<= 1) {
        int u = __shfl_up(ps2, off, 64);
        if (lane >= off) ps2 += u;
    }
    if (lane == 63) wsum[wid] = ps2;
    __syncthreads();
    int wb2 = 0;
    for (int w = 0; w < wid; ++w) wb2 += wsum[w];
    startb[r] = wb2 + ps2 - hv;
    __syncthreads();
    // ---- phase 4: scatter node ids ----
    #pragma unroll
    for (int j = 0; j < 10; ++j) {
        int i = t * 10 + j;
        if (i < NN) {
            int d = v[j] > 1023 ? 1023 : v[j];
            int pos = startb[d] + atomicAdd(&cur[d], 1);
            order[pos] = i;
        }
    }
}

// CSR scatter; also fold attr·(w_e@aw_e)+ab per edge for both layers -> se12[e]
__global__ __launch_bounds__(256) void scatter_kernel(
    const int* __restrict__ ei, const int* __restrict__ offs,
    int* __restrict__ cursor, const float* __restrict__ attr,
    const float* __restrict__ vecs, const float* __restrict__ ab1,
    const float* __restrict__ ab2, int2* __restrict__ recs,
    float2* __restrict__ se12) {
    int e = blockIdx.x * blockDim.x + threadIdx.x;
    if (e >= EE) return;
    int s = ei[e], d = ei[EE + e];
    const float4* ap = (const float4*)(attr + (size_t)e * CE);
    float4 a0 = ap[0], a1 = ap[1], a2 = ap[2], a3 = ap[3];
    const float* v1 = vecs + 128;
    const float* v2 = vecs + 272;
    float s1 = ab1[0], s2 = ab2[0];
    s1 = fmaf(a0.x, v1[0], s1);  s1 = fmaf(a0.y, v1[1], s1);
    s1 = fmaf(a0.z, v1[2], s1);  s1 = fmaf(a0.w, v1[3], s1);
    s1 = fmaf(a1.x, v1[4], s1);  s1 = fmaf(a1.y, v1[5], s1);
    s1 = fmaf(a1.z, v1[6], s1);  s1 = fmaf(a1.w, v1[7], s1);
    s1 = fmaf(a2.x, v1[8], s1);  s1 = fmaf(a2.y, v1[9], s1);
    s1 = fmaf(a2.z, v1[10], s1); s1 = fmaf(a2.w, v1[11], s1);
    s1 = fmaf(a3.x, v1[12], s1); s1 = fmaf(a3.y, v1[13], s1);
    s1 = fmaf(a3.z, v1[14], s1); s1 = fmaf(a3.w, v1[15], s1);
    s2 = fmaf(a0.x, v2[0], s2);  s2 = fmaf(a0.y, v2[1], s2);
    s2 = fmaf(a0.z, v2[2], s2);  s2 = fmaf(a0.w, v2[3], s2);
    s2 = fmaf(a1.x, v2[4], s2);  s2 = fmaf(a1.y, v2[5], s2);
    s2 = fmaf(a1.z, v2[6], s2);  s2 = fmaf(a1.w, v2[7], s2);
    s2 = fmaf(a2.x, v2[8], s2);  s2 = fmaf(a2.y, v2[9], s2);
    s2 = fmaf(a2.z, v2[10], s2); s2 = fmaf(a2.w, v2[11], s2);
    s2 = fmaf(a3.x, v2[12], s2); s2 = fmaf(a3.y, v2[13], s2);
    s2 = fmaf(a3.z, v2[14], s2); s2 = fmaf(a3.w, v2[15], s2);
    int p = atomicAdd(&cursor[d], 1);
    recs[offs[d] + p] = make_int2(s, e);
    se12[e] = make_float2(s1, s2);
}

// xp = x @ w_n ; sa = xp@qa ; sb = xp@ka.  One wave per node, 4 nodes/block.
// (round-0/2 proven version)
__global__ __launch_bounds__(256) void node_prep_kernel(
    const float* __restrict__ x, const float* __restrict__ w_n,
    const float* __restrict__ qa, const float* __restrict__ ka,
    float* __restrict__ xp, float* __restrict__ sa, float* __restrict__ sb) {
    __shared__ float w_sh[64 * 64];     // 16 KB
    __shared__ float x_sh[4 * BB * CC]; // 4 KB
    int t = threadIdx.x;
    for (int i = t; i < 64 * 64; i += 256) w_sh[i] = w_n[i];
    int node0 = blockIdx.x * 4;
    const float4* xg = (const float4*)(x + (size_t)node0 * BB * CC);
    ((float4*)x_sh)[t] = xg[t];
    __syncthreads();
    int wave = t >> 6, lane = t & 63;
    int node = node0 + wave;
    const float* xrow = x_sh + wave * BB * CC;
    float acc0 = 0.f, acc1 = 0.f, acc2 = 0.f, acc3 = 0.f;
    #pragma unroll 8
    for (int ci = 0; ci < 64; ++ci) {
        float w = w_sh[ci * 64 + lane];
        acc0 = fmaf(xrow[ci], w, acc0);
        acc1 = fmaf(xrow[64 + ci], w, acc1);
        acc2 = fmaf(xrow[128 + ci], w, acc2);
        acc3 = fmaf(xrow[192 + ci], w, acc3);
    }
    size_t obase = (size_t)node * BB * CC + lane;
    xp[obase] = acc0;
    xp[obase + 64] = acc1;
    xp[obase + 128] = acc2;
    xp[obase + 192] = acc3;
    float qv = qa[lane], kv = ka[lane];
    float ra0 = acc0 * qv, ra1 = acc1 * qv, ra2 = acc2 * qv, ra3 = acc3 * qv;
    float rb0 = acc0 * kv, rb1 = acc1 * kv, rb2 = acc2 * kv, rb3 = acc3 * kv;
    #pragma unroll
    for (int off = 32; off >= 1; off >>= 1) {
        ra0 += __shfl_xor(ra0, off, 64); ra1 += __shfl_xor(ra1, off, 64);
        ra2 += __shfl_xor(ra2, off, 64); ra3 += __shfl_xor(ra3, off, 64);
        rb0 += __shfl_xor(rb0, off, 64); rb1 += __shfl_xor(rb1, off, 64);
        rb2 += __shfl_xor(rb2, off, 64); rb3 += __shfl_xor(rb3, off, 64);
    }
    if (lane == 0) {
        sa[node * BB + 0] = ra0; sa[node * BB + 1] = ra1;
        sa[node * BB + 2] = ra2; sa[node * BB + 3] = ra3;
        sb[node * BB + 0] = rb0; sb[node * BB + 1] = rb1;
        sb[node * BB + 2] = rb2; sb[node * BB + 3] = rb3;
    }
}

// per-edge attention scalar: att4[e] = sigmoid(sa[src] + sb[dst] + se12[e])
__global__ __launch_bounds__(256) void att_kernel(
    const int* __restrict__ ei, const float2* __restrict__ se12,
    const float* __restrict__ sa, const float* __restrict__ sb,
    float4* __restrict__ att, int sel) {
    int e = blockIdx.x * blockDim.x + threadIdx.x;
    if (e >= EE) return;
    int s = ei[e], d = ei[EE + e];
    float2 se2 = se12[e];
    float se = sel ? se2.y : se2.x;
    float4 sas = *(const float4*)(sa + (size_t)s * BB);
    float4 sbn = *(const float4*)(sb + (size_t)d * BB);
    float4 r;
    r.x = sigmoidf_(sas.x + sbn.x + se);
    r.y = sigmoidf_(sas.y + sbn.y + se);
    r.z = sigmoidf_(sas.z + sbn.z + se);
    r.w = sigmoidf_(sas.w + sbn.w + se);
    att[e] = r;
}

#define FMA4(o_, s_, w_)                                                 \
    o_.x = fmaf(s_, w_.x, o_.x); o_.y = fmaf(s_, w_.y, o_.y);            \
    o_.z = fmaf(s_, w_.z, o_.z); o_.w = fmaf(s_, w_.w, o_.w);

// Per-node segment-max aggregation + output linear + residual + leaky_relu.
// One wave per node (lane = channel in edge loop), 4 nodes/block, degree-sorted.
// Epilogue remapped to lane=(batch, cout/4): segment-max passes through a
// padded-68 LDS tile (4 ds_write_b32 + 16 conflict-free ds_read_b128 per wave
// instead of 520 broadcast b32s); xp row and ow read as float4 from L1/L2.
__global__ __launch_bounds__(256) void conv_out_kernel(
    const float* __restrict__ xp,      // [NN,BB,CC]
    const int2* __restrict__ recs,     // [EE] {src, e}
    const int* __restrict__ offs,      // [NN+1]
    const float* __restrict__ attr,    // [EE,CE]
    const float* __restrict__ w_e,     // [CE,CC]
    const float4* __restrict__ att,    // [EE]
    const float* __restrict__ ow,      // [2*CC,CC]
    const float* __restrict__ ob,      // [CC]
    const int* __restrict__ order,     // [NN] degree-descending node ids
    float* __restrict__ out) {         // [NN,BB,CC]
    __shared__ float aggr_sh[4][BB * 68];  // 4.25 KB; pad 68 -> conflict-free b128
    int t = threadIdx.x;
    int wave = t >> 6, lane = t & 63;
    int node = order[blockIdx.x * 4 + wave];

    float wec[CE];
    #pragma unroll
    for (int j = 0; j < CE; ++j) wec[j] = w_e[j * CC + lane];

    int o0 = offs[node], o1 = offs[node + 1];
    float m0 = -INFINITY, m1 = -INFINITY, m2 = -INFINITY, m3 = -INFINITY;

    int i = o0;
    int2 rec = (i < o1) ? recs[i] : make_int2(0, 0);
    while (i < o1) {
        int2 cur = rec;
        ++i;
        if (i < o1) rec = recs[i];  // prefetch next
        int s = cur.x, e = cur.y;
        float4 at = att[e];
        const float4* ap = (const float4*)(attr + (size_t)e * CE);
        float4 a0 = ap[0], a1 = ap[1], a2 = ap[2], a3 = ap[3];
        float g = 0.f;
        g = fmaf(a0.x, wec[0], g);  g = fmaf(a0.y, wec[1], g);
        g = fmaf(a0.z, wec[2], g);  g = fmaf(a0.w, wec[3], g);
        g = fmaf(a1.x, wec[4], g);  g = fmaf(a1.y, wec[5], g);
        g = fmaf(a1.z, wec[6], g);  g = fmaf(a1.w, wec[7], g);
        g = fmaf(a2.x, wec[8], g);  g = fmaf(a2.y, wec[9], g);
        g = fmaf(a2.z, wec[10], g); g = fmaf(a2.w, wec[11], g);
        g = fmaf(a3.x, wec[12], g); g = fmaf(a3.y, wec[13], g);
        g = fmaf(a3.z, wec[14], g); g = fmaf(a3.w, wec[15], g);
        g = sigmoidf_(g);
        const float* xs = xp + (size_t)s * BB * CC + lane;
        float x0 = xs[0], x1 = xs[64], x2 = xs[128], x3 = xs[192];
        m0 = fmaxf(m0, at.x * x0 * g);
        m1 = fmaxf(m1, at.y * x1 * g);
        m2 = fmaxf(m2, at.z * x2 * g);
        m3 = fmaxf(m3, at.w * x3 * g);
    }
    // empty segments -> 0
    m0 = (m0 == -INFINITY) ? 0.f : m0;
    m1 = (m1 == -INFINITY) ? 0.f : m1;
    m2 = (m2 == -INFINITY) ? 0.f : m2;
    m3 = (m3 == -INFINITY) ? 0.f : m3;

    // wave-private transpose tile (no __syncthreads; in-wave lgkmcnt fence)
    float* ash = aggr_sh[wave];
    ash[0 * 68 + lane] = m0;
    ash[1 * 68 + lane] = m1;
    ash[2 * 68 + lane] = m2;
    ash[3 * 68 + lane] = m3;
    asm volatile("s_waitcnt lgkmcnt(0)" ::: "memory");
    __builtin_amdgcn_sched_barrier(0);

    int b = lane >> 4, q4 = (lane & 15) << 2;
    const float* agr = ash + b * 68;
    const float* xrow = xp + (size_t)node * (BB * CC) + b * CC;  // L1-warm
    const float* owa = ow + q4;
    const float* owb = ow + CC * CC + q4;
    float4 o = make_float4(0.f, 0.f, 0.f, 0.f);
    #pragma unroll 2
    for (int c4 = 0; c4 < 16; ++c4) {
        float4 xv = *(const float4*)(xrow + 4 * c4);   // global broadcast
        float4 av = *(const float4*)(agr + 4 * c4);    // 1 ds_read_b128, 4 addrs
        const float* wpa = owa + (size_t)(4 * c4) * CC;
        float4 w0 = *(const float4*)(wpa);
        float4 w1 = *(const float4*)(wpa + CC);
        float4 w2 = *(const float4*)(wpa + 2 * CC);
        float4 w3 = *(const float4*)(wpa + 3 * CC);
        const float* wpb = owb + (size_t)(4 * c4) * CC;
        float4 u0 = *(const float4*)(wpb);
        float4 u1 = *(const float4*)(wpb + CC);
        float4 u2 = *(const float4*)(wpb + 2 * CC);
        float4 u3 = *(const float4*)(wpb + 3 * CC);
        FMA4(o, xv.x, w0); FMA4(o, xv.y, w1); FMA4(o, xv.z, w2); FMA4(o, xv.w, w3);
        FMA4(o, av.x, u0); FMA4(o, av.y, u1); FMA4(o, av.z, u2); FMA4(o, av.w, u3);
    }
    float4 xnv = *(const float4*)(xrow + q4);
    float4 ob4 = *(const float4*)(ob + q4);
    float4 r;
    r.x = xnv.x + o.x + ob4.x;
    r.y = xnv.y + o.y + ob4.y;
    r.z = xnv.z + o.z + ob4.z;
    r.w = xnv.w + o.w + ob4.w;
    r.x = (r.x > 0.f) ? r.x : 0.01f * r.x;
    r.y = (r.y > 0.f) ? r.y : 0.01f * r.y;
    r.z = (r.z > 0.f) ? r.z : 0.01f * r.z;
    r.w = (r.w > 0.f) ? r.w : 0.01f * r.w;
    *(float4*)(out + (size_t)node * (BB * CC) + b * CC + q4) = r;
}

extern "C" void kernel_launch(void* const* d_in, const int* in_sizes, int n_in,
                              void* d_out, int out_size, void* d_ws, size_t ws_size,
                              hipStream_t stream) {
    const float* X    = (const float*)d_in[0];
    const int*   ei   = (const int*)d_in[1];
    const float* attr = (const float*)d_in[2];
    const float* w_n1 = (const float*)d_in[3];
    const float* w_e1 = (const float*)d_in[4];
    const float* q1   = (const float*)d_in[5];
    const float* k1   = (const float*)d_in[6];
    const float* aw1  = (const float*)d_in[7];
    const float* ab1  = (const float*)d_in[8];
    const float* ow1  = (const float*)d_in[9];
    const float* ob1  = (const float*)d_in[10];
    const float* w_n2 = (const float*)d_in[11];
    const float* w_e2 = (const float*)d_in[12];
    const float* q2   = (const float*)d_in[13];
    const float* k2   = (const float*)d_in[14];
    const float* aw2  = (const float*)d_in[15];
    const float* ab2  = (const float*)d_in[16];
    const float* ow2  = (const float*)d_in[17];
    const float* ob2  = (const float*)d_in[18];
    float* out = (float*)d_out;

    char* ws = (char*)d_ws;
    float*  xpA    = (float*)(ws + OFF_XPA);
    float*  xpB    = (float*)(ws + OFF_XPB);
    float*  sa     = (float*)(ws + OFF_SA);
    float*  sb     = (float*)(ws + OFF_SB);
    float*  vecs   = (float*)(ws + OFF_VECS);
    int*    counts = (int*)(ws + OFF_COUNTS);
    int*    cursor = (int*)(ws + OFF_CURSOR);
    int*    offs   = (int*)(ws + OFF_OFFS);
    int2*   recs   = (int2*)(ws + OFF_RECS);
    float4* att    = (float4*)(ws + OFF_ATT);
    float2* se12   = (float2*)(ws + OFF_SE12);
    int*    order  = (int*)(ws + OFF_ORDER);

    // CSR build (edge_index is layer-invariant)
    hipMemsetAsync(counts, 0, 2 * NN * sizeof(int), stream);  // counts + cursor
    hist_vecs_kernel<<<EE / 256, 256, 0, stream>>>(ei, counts, q1, k1, aw1, w_e1,
                                                   q2, k2, aw2, w_e2, vecs);
    scan_order_kernel<<<1, 1024, 0, stream>>>(counts, offs, order);
    scatter_kernel<<<EE / 256, 256, 0, stream>>>(ei, offs, cursor, attr, vecs,
                                                 ab1, ab2, recs, se12);
    // layer 1
    node_prep_kernel<<<NN / 4, 256, 0, stream>>>(X, w_n1, vecs + 0, vecs + 64, xpA, sa, sb);
    att_kernel<<<EE / 256, 256, 0, stream>>>(ei, se12, sa, sb, att, 0);
    conv_out_kernel<<<NN / 4, 256, 0, stream>>>(xpA, recs, offs, attr, w_e1, att,
                                                ow1, ob1, order, xpB);
    // layer 2
    node_prep_kernel<<<NN / 4, 256, 0, stream>>>(xpB, w_n2, vecs + 144, vecs + 208, xpA, sa, sb);
    att_kernel<<<EE / 256, 256, 0, stream>>>(ei, se12, sa, sb, att, 1);
    conv_out_kernel<<<NN / 4, 256, 0, stream>>>(xpA, recs, offs, attr, w_e2, att,
                                                ow2, ob2, order, out);
}